// Round 22
// baseline (119.546 us; speedup 1.0000x reference)
//
#include <hip/hip_runtime.h>
#include <hip/hip_bf16.h>
#include <math.h>

// B=8, T=1024, C=768, H=12, D=64
#define Bq 8
#define Tq 1024
#define Cq 768
#define Hq 12
#define Dq 64
#define MROWS (Bq*Tq)      // 8192
#define N_QKV (3*Cq)       // 2304

typedef __bf16 bf16;
typedef bf16 bf16x8 __attribute__((ext_vector_type(8)));
typedef bf16 bf16x4 __attribute__((ext_vector_type(4)));
typedef float f32x4 __attribute__((ext_vector_type(4)));
typedef float f32x16 __attribute__((ext_vector_type(16)));
typedef unsigned int u32x4 __attribute__((ext_vector_type(4)));

#define MFMA16x16x32(a, b, c) __builtin_amdgcn_mfma_f32_16x16x32_bf16((a), (b), (c), 0, 0, 0)
#define MFMA32x32x16(a, b, c) __builtin_amdgcn_mfma_f32_32x32x16_bf16((a), (b), (c), 0, 0, 0)

// counted vmcnt wait (T4): literal N, memory clobber orders following ds ops
#define WAITVM(N) asm volatile("s_waitcnt vmcnt(" #N ")" ::: "memory")

// LDS tiles (staging) have 128-byte rows; XOR-swizzle 16B chunks by row (T2).
__device__ __forceinline__ bf16x8& lds_v8(bf16* base, int row, int byteoff) {
    return *reinterpret_cast<bf16x8*>(
        reinterpret_cast<char*>(base) + row * 128 + (byteoff ^ ((row & 7) << 4)));
}

typedef __attribute__((address_space(3))) unsigned int lds_u32;
typedef const __attribute__((address_space(1))) unsigned int glb_u32;
__device__ __forceinline__ void gload16(const void* g, void* lds) {
    __builtin_amdgcn_global_load_lds((glb_u32*)(uintptr_t)g,
                                     (lds_u32*)(unsigned int)(uintptr_t)lds,
                                     16, 0, 0);
}

__device__ __forceinline__ unsigned cvtpk_bf16(float lo, float hi) {
    unsigned r;
    asm volatile("v_cvt_pk_bf16_f32 %0, %1, %2" : "=v"(r) : "v"(lo), "v"(hi));
    return r;
}

// v_permlane32_swap_b32: a' = {a[0:31], b[0:31]}, b' = {a[32:63], b[32:63]}
__device__ __forceinline__ void permlane32_swap(unsigned& a, unsigned& b) {
    asm("v_permlane32_swap_b32 %0, %1" : "+v"(a), "+v"(b));
}

// ---------------- fused prep: x->bf16 + both weight transposes --------------
#define NA_CONV 3072   // (8192*768/8)/256
#define NB_WA   432    // (2304/64)*(768/64)
#define NB_WP   144    // (768/64)*(768/64)
__global__ __launch_bounds__(256) void prep(const float* __restrict__ x,
                                            const float* __restrict__ wa,
                                            const float* __restrict__ wp,
                                            bf16* __restrict__ Ax,
                                            bf16* __restrict__ WaT,
                                            bf16* __restrict__ WpT) {
    __shared__ float tile[64][65];
    const int bid = blockIdx.x;
    if (bid < NA_CONV) {
        const int i = bid * 256 + threadIdx.x;
        const float4* p = reinterpret_cast<const float4*>(x) + (size_t)i * 2;
        float4 a = p[0], b = p[1];
        bf16x8 o;
        o[0] = (bf16)a.x; o[1] = (bf16)a.y; o[2] = (bf16)a.z; o[3] = (bf16)a.w;
        o[4] = (bf16)b.x; o[5] = (bf16)b.y; o[6] = (bf16)b.z; o[7] = (bf16)b.w;
        reinterpret_cast<bf16x8*>(Ax)[i] = o;
        return;
    }
    const float* src;
    bf16* dst;
    int C, tb, bxT;
    if (bid < NA_CONV + NB_WA) { tb = bid - NA_CONV; src = wa; dst = WaT; C = N_QKV; bxT = 36; }
    else                       { tb = bid - NA_CONV - NB_WA; src = wp; dst = WpT; C = Cq; bxT = 12; }
    const int R = Cq;
    const int bx = (tb % bxT) * 64, by = (tb / bxT) * 64;
    const int tx = threadIdx.x & 63, ty = threadIdx.x >> 6;
    #pragma unroll
    for (int i = 0; i < 64; i += 4)
        tile[ty + i][tx] = src[(size_t)(by + ty + i) * C + bx + tx];
    __syncthreads();
    #pragma unroll
    for (int i = 0; i < 64; i += 4)
        dst[(size_t)(bx + ty + i) * R + by + tx] = (bf16)tile[tx][ty + i];
}

// ---------------- QKV GEMM: 128x128, 3-buf counted-vmcnt + staged epilogue ---
// K out: K8 [B,H,D/8,T,8]; V out: V8 [B,H,T/8,D,8]  (fragment-native layouts)
__global__ __launch_bounds__(256) void gemm_qkv(const bf16* __restrict__ A,
                                                const bf16* __restrict__ Bt,
                                                const float* __restrict__ bias,
                                                bf16* __restrict__ Qo,
                                                bf16* __restrict__ K8,
                                                bf16* __restrict__ V8) {
    __shared__ bf16 As[3][128 * 64];   // 3 x 16 KB
    __shared__ bf16 Bs[3][128 * 64];   // 3 x 16 KB
    const int tid = threadIdx.x;
    const int w = tid >> 6, l = tid & 63;
    const int lane16 = l & 15, kg = l >> 4;
    const int wr = w >> 1, wc = w & 1;
    const int flat = blockIdx.x;
    const int nid = (flat & 7) * 144 + (flat >> 3);
    const int bn0 = (nid % 18) * 128, bm0 = (nid / 18) * 128;

    auto stage = [&](int k0, int buf) {
        #pragma unroll
        for (int j = 0; j < 4; ++j) {
            const int q8 = w * 4 + j;
            const int r  = q8 * 8 + (l >> 3);
            const int c16 = (l & 7) ^ (r & 7);
            gload16(A + (size_t)(bm0 + r) * Cq + k0 + c16 * 8, &As[buf][q8 * 512]);
            gload16(Bt + (size_t)(bn0 + r) * Cq + k0 + c16 * 8, &Bs[buf][q8 * 512]);
        }
    };

    f32x4 acc[4][4] = {};
    stage(0, 0);
    stage(64, 1);
    #pragma unroll
    for (int kt = 0; kt < 12; ++kt) {
        if (kt < 11) { WAITVM(8); } else { WAITVM(0); }  // stage(kt) landed;
        __builtin_amdgcn_s_barrier();                    // stage(kt+1) in flight
        bf16* Ac = As[kt % 3];
        bf16* Bc = Bs[kt % 3];
        #pragma unroll
        for (int ks = 0; ks < 2; ++ks) {
            bf16x8 af[4], bfr[4];
            #pragma unroll
            for (int m = 0; m < 4; ++m)
                af[m] = lds_v8(Ac, wr * 64 + m * 16 + lane16, ks * 64 + kg * 16);
            #pragma unroll
            for (int n = 0; n < 4; ++n)
                bfr[n] = lds_v8(Bc, wc * 64 + n * 16 + lane16, ks * 64 + kg * 16);
            #pragma unroll
            for (int m = 0; m < 4; ++m)
                #pragma unroll
                for (int n = 0; n < 4; ++n)
                    acc[m][n] = MFMA16x16x32(af[m], bfr[n], acc[m][n]);
        }
        if (kt + 2 < 12) stage((kt + 2) * 64, (kt + 2) % 3);  // depth-2 prefetch
    }
    __syncthreads();   // all waves done with LDS before epilogue reuse

    const int whichB = bn0 / Cq;               // 0=Q 1=K 2=V, block-uniform
    char* Lt = (char*)&As[0][0];               // 32 KB reuse (As[0..1])
    #pragma unroll
    for (int mi = 0; mi < 4; ++mi) {
        #pragma unroll
        for (int r = 0; r < 4; ++r) {
            const int m = wr * 64 + mi * 16 + kg * 4 + r;
            #pragma unroll
            for (int ni = 0; ni < 4; ++ni) {
                const int n = wc * 64 + ni * 16 + lane16;
                float v = acc[mi][ni][r] + bias[bn0 + n];
                if (whichB == 0) v *= 0.18033688011112042f;  // 1/8 * log2(e)
                int a;
                if (whichB < 2) a = m * 256 + ((n * 2) ^ ((m & 7) << 4));
                else            a = n * 256 + ((m * 2) ^ ((n & 7) << 4));
                *reinterpret_cast<bf16*>(Lt + a) = (bf16)v;
            }
        }
    }
    __syncthreads();
    const int bb = bm0 >> 10, tt0 = bm0 & 1023;
    if (whichB == 0) {
        #pragma unroll
        for (int j = 0; j < 8; ++j) {
            const int c = j * 256 + tid;       // 2048 16B-chunks
            const int m = c >> 4, nc = c & 15;
            bf16x8 val = *reinterpret_cast<bf16x8*>(Lt + m * 256 + ((nc * 16) ^ ((m & 7) << 4)));
            const int gcol0 = bn0 + nc * 8;
            const int h = gcol0 >> 6;
            const int d0 = gcol0 & 63;
            *reinterpret_cast<bf16x8*>(Qo + (((size_t)bb * Hq + h) * Tq + tt0 + m) * Dq + d0) = val;
        }
    } else if (whichB == 1) {
        // K8: chunk = 8 consecutive d at one t; consecutive m -> contiguous
        #pragma unroll
        for (int j = 0; j < 8; ++j) {
            const int c = j * 256 + tid;
            const int m = c & 127, nc = c >> 7;
            bf16x8 val = *reinterpret_cast<bf16x8*>(Lt + m * 256 + ((nc * 16) ^ ((m & 7) << 4)));
            const int hn = bn0 + nc * 8 - Cq;
            const int h = hn >> 6, d8 = (hn >> 3) & 7;
            *reinterpret_cast<bf16x8*>(
                K8 + ((((size_t)bb * Hq + h) * 8 + d8) * Tq + tt0 + m) * 8) = val;
        }
    } else {
        // V8: chunk = 8 consecutive t at one d; consecutive d -> contiguous
        #pragma unroll
        for (int j = 0; j < 8; ++j) {
            const int c = j * 256 + tid;
            const int d6 = c & 63, rest = c >> 6;
            const int hh = rest & 1, mc = rest >> 1;
            const int n = hh * 64 + d6;
            bf16x8 val = *reinterpret_cast<bf16x8*>(Lt + n * 256 + ((mc * 16) ^ ((n & 7) << 4)));
            const int hn = bn0 + n - 2 * Cq;
            const int h = hn >> 6, d = hn & 63;
            *reinterpret_cast<bf16x8*>(
                V8 + ((((size_t)bb * Hq + h) * 128 + (tt0 >> 3) + mc) * Dq + d) * 8) = val;
        }
    }
}

// ---------------- Flash causal attention: 32-row waves + T13 defer-max -------
__global__ __launch_bounds__(256) void attn_mfma(const bf16* __restrict__ Q,
                                                 const bf16* __restrict__ K8,
                                                 const bf16* __restrict__ V8,
                                                 bf16* __restrict__ Y) {
    const int tid = threadIdx.x;
    const int w = tid >> 6, l = tid & 63;
    const int l31 = l & 31, hi = l >> 5;
    const int g = blockIdx.x / 96;             // 0..7, heaviest first
    const int bh = blockIdx.x % 96;            // same head -> same XCD (96%8==0)
    const int qs = 31 - (g * 4 + w);           // q32-subtile 0..31
    const int q0 = qs * 32;
    const int nt = (qs >> 1) + 1;              // KV 64-tiles
    const size_t hoff = (size_t)bh * Tq * Dq;
    const size_t base8 = (size_t)bh * (Tq * Dq);
    const int q0g = q0 + l31;                  // this lane's global q row

    bf16x8 qf[4];
    #pragma unroll
    for (int ds = 0; ds < 4; ++ds)
        qf[ds] = *reinterpret_cast<const bf16x8*>(
            Q + hoff + (size_t)q0g * Dq + ds * 16 + hi * 8);

    f32x16 o[2] = {};                           // [dh]
    float m_ = -INFINITY, l_ = 0.f;

    for (int t = 0; t < nt; ++t) {
        const bool diag = (t == nt - 1);
        const bool half = diag && !(qs & 1);    // upper 32 kcols fully masked
        bf16x8 kf[2][4];
        #pragma unroll
        for (int ds = 0; ds < 4; ++ds)
            kf[0][ds] = *reinterpret_cast<const bf16x8*>(
                K8 + base8 + ((size_t)(ds * 2 + hi) * Tq + t * 64 + l31) * 8);
        if (!half) {
            #pragma unroll
            for (int ds = 0; ds < 4; ++ds)
                kf[1][ds] = *reinterpret_cast<const bf16x8*>(
                    K8 + base8 + ((size_t)(ds * 2 + hi) * Tq + t * 64 + 32 + l31) * 8);
        }
        bf16x8 vf[4][2];
        #pragma unroll
        for (int ks = 0; ks < 2; ++ks)
            #pragma unroll
            for (int dh = 0; dh < 2; ++dh)
                vf[ks][dh] = *reinterpret_cast<const bf16x8*>(
                    V8 + base8 + ((size_t)(t * 8 + ks * 2 + hi) * Dq + dh * 32 + l31) * 8);
        if (!half) {
            #pragma unroll
            for (int ks = 2; ks < 4; ++ks)
                #pragma unroll
                for (int dh = 0; dh < 2; ++dh)
                    vf[ks][dh] = *reinterpret_cast<const bf16x8*>(
                        V8 + base8 + ((size_t)(t * 8 + ks * 2 + hi) * Dq + dh * 32 + l31) * 8);
        }

        f32x16 s[2] = {};
        #pragma unroll
        for (int ds = 0; ds < 4; ++ds) s[0] = MFMA32x32x16(kf[0][ds], qf[ds], s[0]);
        if (!half) {
            #pragma unroll
            for (int ds = 0; ds < 4; ++ds) s[1] = MFMA32x32x16(kf[1][ds], qf[ds], s[1]);
        }
        if (diag) {
            #pragma unroll
            for (int reg = 0; reg < 16; ++reg) {
                const int kg_ = t * 64 + (reg & 3) + 8 * (reg >> 2) + 4 * hi;
                if (kg_ > q0g) s[0][reg] = -INFINITY;
                if (!half && kg_ + 32 > q0g) s[1][reg] = -INFINITY;
            }
        }
        // 4-way tree max
        float pm0 = -INFINITY, pm1 = -INFINITY, pm2 = -INFINITY, pm3 = -INFINITY;
        #pragma unroll
        for (int reg = 0; reg < 16; reg += 4) {
            pm0 = fmaxf(pm0, s[0][reg + 0]);
            pm1 = fmaxf(pm1, s[0][reg + 1]);
            pm2 = fmaxf(pm2, s[0][reg + 2]);
            pm3 = fmaxf(pm3, s[0][reg + 3]);
        }
        if (!half) {
            #pragma unroll
            for (int reg = 0; reg < 16; reg += 4) {
                pm0 = fmaxf(pm0, s[1][reg + 0]);
                pm1 = fmaxf(pm1, s[1][reg + 1]);
                pm2 = fmaxf(pm2, s[1][reg + 2]);
                pm3 = fmaxf(pm3, s[1][reg + 3]);
            }
        }
        float pmax = fmaxf(fmaxf(pm0, pm1), fmaxf(pm2, pm3));
        pmax = fmaxf(pmax, __shfl_xor(pmax, 32));
        // T13 defer-max: rescale only when max grew beyond headroom.
        if (!__all(pmax <= m_ + 8.f)) {
            const float mn = fmaxf(m_, pmax);
            const float alpha = exp2f(m_ - mn);
            m_ = mn;
            l_ *= alpha;
            o[0] *= alpha;
            o[1] *= alpha;
        }
        // 4-way tree sum
        float ls0 = 0.f, ls1 = 0.f, ls2 = 0.f, ls3 = 0.f;
        #pragma unroll
        for (int reg = 0; reg < 16; reg += 4) {
            const float p0 = exp2f(s[0][reg + 0] - m_);
            const float p1 = exp2f(s[0][reg + 1] - m_);
            const float p2 = exp2f(s[0][reg + 2] - m_);
            const float p3 = exp2f(s[0][reg + 3] - m_);
            s[0][reg + 0] = p0; ls0 += p0;
            s[0][reg + 1] = p1; ls1 += p1;
            s[0][reg + 2] = p2; ls2 += p2;
            s[0][reg + 3] = p3; ls3 += p3;
        }
        if (!half) {
            #pragma unroll
            for (int reg = 0; reg < 16; reg += 4) {
                const float p0 = exp2f(s[1][reg + 0] - m_);
                const float p1 = exp2f(s[1][reg + 1] - m_);
                const float p2 = exp2f(s[1][reg + 2] - m_);
                const float p3 = exp2f(s[1][reg + 3] - m_);
                s[1][reg + 0] = p0; ls0 += p0;
                s[1][reg + 1] = p1; ls1 += p1;
                s[1][reg + 2] = p2; ls2 += p2;
                s[1][reg + 3] = p3; ls3 += p3;
            }
        }
        l_ += (ls0 + ls1) + (ls2 + ls3);
        // P-pack via permlane32_swap
        bf16x8 pa[4];
        #pragma unroll
        for (int g2 = 0; g2 < 2; ++g2) {
            const int rb = g2 * 8;
            unsigned u01 = cvtpk_bf16(s[0][rb + 0], s[0][rb + 1]);
            unsigned u23 = cvtpk_bf16(s[0][rb + 2], s[0][rb + 3]);
            unsigned u45 = cvtpk_bf16(s[0][rb + 4], s[0][rb + 5]);
            unsigned u67 = cvtpk_bf16(s[0][rb + 6], s[0][rb + 7]);
            permlane32_swap(u01, u45);
            permlane32_swap(u23, u67);
            u32x4 wv;
            wv[0] = u01; wv[1] = u23; wv[2] = u45; wv[3] = u67;
            pa[g2] = __builtin_bit_cast(bf16x8, wv);
        }
        if (!half) {
            #pragma unroll
            for (int g2 = 0; g2 < 2; ++g2) {
                const int rb = g2 * 8;
                unsigned u01 = cvtpk_bf16(s[1][rb + 0], s[1][rb + 1]);
                unsigned u23 = cvtpk_bf16(s[1][rb + 2], s[1][rb + 3]);
                unsigned u45 = cvtpk_bf16(s[1][rb + 4], s[1][rb + 5]);
                unsigned u67 = cvtpk_bf16(s[1][rb + 6], s[1][rb + 7]);
                permlane32_swap(u01, u45);
                permlane32_swap(u23, u67);
                u32x4 wv;
                wv[0] = u01; wv[1] = u23; wv[2] = u45; wv[3] = u67;
                pa[2 + g2] = __builtin_bit_cast(bf16x8, wv);
            }
        }
        #pragma unroll
        for (int ks = 0; ks < 2; ++ks)
            #pragma unroll
            for (int dh = 0; dh < 2; ++dh)
                o[dh] = MFMA32x32x16(vf[ks][dh], pa[ks], o[dh]);
        if (!half) {
            #pragma unroll
            for (int ks = 2; ks < 4; ++ks)
                #pragma unroll
                for (int dh = 0; dh < 2; ++dh)
                    o[dh] = MFMA32x32x16(vf[ks][dh], pa[ks], o[dh]);
        }
    }

    const int bb = bh / Hq, h = bh - bb * Hq;
    const float ltot = l_ + __shfl_xor(l_, 32);
    const float inv = 1.f / ltot;
    bf16* yp = Y + ((size_t)bb * Tq + q0g) * Cq + h * Dq;
    #pragma unroll
    for (int dh = 0; dh < 2; ++dh)
        #pragma unroll
        for (int rg = 0; rg < 4; ++rg) {
            const int d0 = 8 * rg + 4 * hi + 32 * dh;
            bf16x4 ov;
            #pragma unroll
            for (int j = 0; j < 4; ++j) ov[j] = (bf16)(o[dh][rg * 4 + j] * inv);
            *reinterpret_cast<bf16x4*>(yp + d0) = ov;
        }
}

// ---------------- Proj GEMM: 128x128 dbuf + LDS-staged f32 epilogue ----------
__global__ __launch_bounds__(256) void gemm_proj(const bf16* __restrict__ A,
                                                 const bf16* __restrict__ Bt,
                                                 const float* __restrict__ bias,
                                                 float* __restrict__ out) {
    __shared__ bf16 As[2][128 * 64];
    __shared__ bf16 Bs[2][128 * 64];
    const int tid = threadIdx.x;
    const int w = tid >> 6, l = tid & 63;
    const int lane16 = l & 15, kg = l >> 4;
    const int wr = w >> 1, wc = w & 1;
    const int flat = blockIdx.x;
    const int nid = (flat & 7) * 48 + (flat >> 3);
    const int bn0 = (nid % 6) * 128, bm0 = (nid / 6) * 128;

    auto stage = [&](int k0, int buf) {
        #pragma unroll
        for (int j = 0; j < 4; ++j) {
            const int q8 = w * 4 + j;
            const int r  = q8 * 8 + (l >> 3);
            const int c16 = (l & 7) ^ (r & 7);
            gload16(A + (size_t)(bm0 + r) * Cq + k0 + c16 * 8, &As[buf][q8 * 512]);
            gload16(Bt + (size_t)(bn0 + r) * Cq + k0 + c16 * 8, &Bs[buf][q8 * 512]);
        }
    };

    f32x4 acc[4][4] = {};
    stage(0, 0);
    __syncthreads();
    for (int kt = 0; kt < 12; ++kt) {
        if (kt < 11) stage((kt + 1) * 64, (kt + 1) & 1);
        bf16* Ac = As[kt & 1];
        bf16* Bc = Bs[kt & 1];
        #pragma unroll
        for (int ks = 0; ks < 2; ++ks) {
            bf16x8 af[4], bfr[4];
            #pragma unroll
            for (int m = 0; m < 4; ++m)
                af[m] = lds_v8(Ac, wr * 64 + m * 16 + lane16, ks * 64 + kg * 16);
            #pragma unroll
            for (int n = 0; n < 4; ++n)
                bfr[n] = lds_v8(Bc, wc * 64 + n * 16 + lane16, ks * 64 + kg * 16);
            #pragma unroll
            for (int m = 0; m < 4; ++m)
                #pragma unroll
                for (int n = 0; n < 4; ++n)
                    acc[m][n] = MFMA16x16x32(af[m], bfr[n], acc[m][n]);
        }
        __syncthreads();
    }

    char* L32 = (char*)&As[0][0];   // 32 KB: 128 rows x 64 f32 (256B rows)
    #pragma unroll
    for (int half = 0; half < 2; ++half) {
        if (wc == half) {
            #pragma unroll
            for (int mi = 0; mi < 4; ++mi)
                #pragma unroll
                for (int r = 0; r < 4; ++r) {
                    const int m = wr * 64 + mi * 16 + kg * 4 + r;
                    #pragma unroll
                    for (int ni = 0; ni < 4; ++ni) {
                        const int nl = ni * 16 + lane16;
                        const float v = acc[mi][ni][r] + bias[bn0 + half * 64 + nl];
                        *reinterpret_cast<float*>(L32 + m * 256 + ((nl * 4) ^ ((m & 7) << 4))) = v;
                    }
                }
        }
        __syncthreads();
        #pragma unroll
        for (int j = 0; j < 8; ++j) {
            const int c = j * 256 + tid;
            const int m = c >> 4, nc = c & 15;
            float4 val = *reinterpret_cast<float4*>(L32 + m * 256 + ((nc * 16) ^ ((m & 7) << 4)));
            *reinterpret_cast<float4*>(out + (size_t)(bm0 + m) * Cq + bn0 + half * 64 + nc * 4) = val;
        }
        __syncthreads();
    }
}

extern "C" void kernel_launch(void* const* d_in, const int* in_sizes, int n_in,
                              void* d_out, int out_size, void* d_ws, size_t ws_size,
                              hipStream_t stream) {
    const float* x      = (const float*)d_in[0];
    const float* w_attn = (const float*)d_in[1];
    const float* b_attn = (const float*)d_in[2];
    const float* w_proj = (const float*)d_in[3];
    const float* b_proj = (const float*)d_in[4];
    float* out = (float*)d_out;

    char* ws = (char*)d_ws;
    bf16* Ax  = (bf16*)ws; ws += (size_t)MROWS * Cq * 2;
    bf16* WaT = (bf16*)ws; ws += (size_t)N_QKV * Cq * 2;
    bf16* WpT = (bf16*)ws; ws += (size_t)Cq * Cq * 2;
    bf16* Qw  = (bf16*)ws; ws += (size_t)MROWS * Cq * 2;   // [B,H,T,D], x0.125*log2e
    bf16* K8w = (bf16*)ws; ws += (size_t)MROWS * Cq * 2;   // [B,H,D/8,T,8]
    bf16* V8w = (bf16*)ws; ws += (size_t)MROWS * Cq * 2;   // [B,H,T/8,D,8]
    bf16* Yw  = (bf16*)ws; ws += (size_t)MROWS * Cq * 2;   // attn out [M][C]

    prep<<<dim3(NA_CONV + NB_WA + NB_WP), 256, 0, stream>>>(x, w_attn, w_proj, Ax, WaT, WpT);
    gemm_qkv<<<dim3(1152), 256, 0, stream>>>(Ax, WaT, b_attn, Qw, K8w, V8w);
    attn_mfma<<<dim3(768), 256, 0, stream>>>(Qw, K8w, V8w, Yw);
    gemm_proj<<<dim3(384), 256, 0, stream>>>(Yw, WpT, b_proj, out);
}

// Round 23
// 106.803 us; speedup vs baseline: 1.1193x; 1.1193x over previous
//
#include <hip/hip_runtime.h>
#include <hip/hip_bf16.h>
#include <math.h>

// B=8, T=1024, C=768, H=12, D=64
#define Bq 8
#define Tq 1024
#define Cq 768
#define Hq 12
#define Dq 64
#define MROWS (Bq*Tq)      // 8192
#define N_QKV (3*Cq)       // 2304

typedef __bf16 bf16;
typedef bf16 bf16x8 __attribute__((ext_vector_type(8)));
typedef bf16 bf16x4 __attribute__((ext_vector_type(4)));
typedef float f32x4 __attribute__((ext_vector_type(4)));
typedef float f32x16 __attribute__((ext_vector_type(16)));
typedef unsigned int u32x4 __attribute__((ext_vector_type(4)));

#define MFMA16x16x32(a, b, c) __builtin_amdgcn_mfma_f32_16x16x32_bf16((a), (b), (c), 0, 0, 0)
#define MFMA32x32x16(a, b, c) __builtin_amdgcn_mfma_f32_32x32x16_bf16((a), (b), (c), 0, 0, 0)

// LDS tiles (staging) have 128-byte rows; XOR-swizzle 16B chunks by row (T2).
__device__ __forceinline__ bf16x8& lds_v8(bf16* base, int row, int byteoff) {
    return *reinterpret_cast<bf16x8*>(
        reinterpret_cast<char*>(base) + row * 128 + (byteoff ^ ((row & 7) << 4)));
}

typedef __attribute__((address_space(3))) unsigned int lds_u32;
typedef const __attribute__((address_space(1))) unsigned int glb_u32;
__device__ __forceinline__ void gload16(const void* g, void* lds) {
    __builtin_amdgcn_global_load_lds((glb_u32*)(uintptr_t)g,
                                     (lds_u32*)(unsigned int)(uintptr_t)lds,
                                     16, 0, 0);
}

__device__ __forceinline__ unsigned cvtpk_bf16(float lo, float hi) {
    unsigned r;
    asm volatile("v_cvt_pk_bf16_f32 %0, %1, %2" : "=v"(r) : "v"(lo), "v"(hi));
    return r;
}

// v_permlane32_swap_b32: a' = {a[0:31], b[0:31]}, b' = {a[32:63], b[32:63]}
__device__ __forceinline__ void permlane32_swap(unsigned& a, unsigned& b) {
    asm("v_permlane32_swap_b32 %0, %1" : "+v"(a), "+v"(b));
}

// ---------------- fused prep: x->bf16 + both weight transposes --------------
#define NA_CONV 3072   // (8192*768/8)/256
#define NB_WA   432    // (2304/64)*(768/64)
#define NB_WP   144    // (768/64)*(768/64)
__global__ __launch_bounds__(256) void prep(const float* __restrict__ x,
                                            const float* __restrict__ wa,
                                            const float* __restrict__ wp,
                                            bf16* __restrict__ Ax,
                                            bf16* __restrict__ WaT,
                                            bf16* __restrict__ WpT) {
    __shared__ float tile[64][65];
    const int bid = blockIdx.x;
    if (bid < NA_CONV) {
        const int i = bid * 256 + threadIdx.x;
        const float4* p = reinterpret_cast<const float4*>(x) + (size_t)i * 2;
        float4 a = p[0], b = p[1];
        bf16x8 o;
        o[0] = (bf16)a.x; o[1] = (bf16)a.y; o[2] = (bf16)a.z; o[3] = (bf16)a.w;
        o[4] = (bf16)b.x; o[5] = (bf16)b.y; o[6] = (bf16)b.z; o[7] = (bf16)b.w;
        reinterpret_cast<bf16x8*>(Ax)[i] = o;
        return;
    }
    const float* src;
    bf16* dst;
    int C, tb, bxT;
    if (bid < NA_CONV + NB_WA) { tb = bid - NA_CONV; src = wa; dst = WaT; C = N_QKV; bxT = 36; }
    else                       { tb = bid - NA_CONV - NB_WA; src = wp; dst = WpT; C = Cq; bxT = 12; }
    const int R = Cq;
    const int bx = (tb % bxT) * 64, by = (tb / bxT) * 64;
    const int tx = threadIdx.x & 63, ty = threadIdx.x >> 6;
    #pragma unroll
    for (int i = 0; i < 64; i += 4)
        tile[ty + i][tx] = src[(size_t)(by + ty + i) * C + bx + tx];
    __syncthreads();
    #pragma unroll
    for (int i = 0; i < 64; i += 4)
        dst[(size_t)(bx + ty + i) * R + by + tx] = (bf16)tile[tx][ty + i];
}

// ---------------- QKV GEMM: 128x128 dbuf + LDS-staged epilogue ---------------
// K out: K8 [B,H,D/8,T,8]; V out: V8 [B,H,T/8,D,8]  (fragment-native layouts)
__global__ __launch_bounds__(256) void gemm_qkv(const bf16* __restrict__ A,
                                                const bf16* __restrict__ Bt,
                                                const float* __restrict__ bias,
                                                bf16* __restrict__ Qo,
                                                bf16* __restrict__ K8,
                                                bf16* __restrict__ V8) {
    __shared__ bf16 As[2][128 * 64];
    __shared__ bf16 Bs[2][128 * 64];
    const int tid = threadIdx.x;
    const int w = tid >> 6, l = tid & 63;
    const int lane16 = l & 15, kg = l >> 4;
    const int wr = w >> 1, wc = w & 1;
    const int flat = blockIdx.x;
    const int nid = (flat & 7) * 144 + (flat >> 3);
    const int bn0 = (nid % 18) * 128, bm0 = (nid / 18) * 128;

    auto stage = [&](int k0, int buf) {
        #pragma unroll
        for (int j = 0; j < 4; ++j) {
            const int q8 = w * 4 + j;
            const int r  = q8 * 8 + (l >> 3);
            const int c16 = (l & 7) ^ (r & 7);
            gload16(A + (size_t)(bm0 + r) * Cq + k0 + c16 * 8, &As[buf][q8 * 512]);
            gload16(Bt + (size_t)(bn0 + r) * Cq + k0 + c16 * 8, &Bs[buf][q8 * 512]);
        }
    };

    f32x4 acc[4][4] = {};
    stage(0, 0);
    __syncthreads();
    for (int kt = 0; kt < 12; ++kt) {
        if (kt < 11) stage((kt + 1) * 64, (kt + 1) & 1);
        bf16* Ac = As[kt & 1];
        bf16* Bc = Bs[kt & 1];
        #pragma unroll
        for (int ks = 0; ks < 2; ++ks) {
            bf16x8 af[4], bfr[4];
            #pragma unroll
            for (int m = 0; m < 4; ++m)
                af[m] = lds_v8(Ac, wr * 64 + m * 16 + lane16, ks * 64 + kg * 16);
            #pragma unroll
            for (int n = 0; n < 4; ++n)
                bfr[n] = lds_v8(Bc, wc * 64 + n * 16 + lane16, ks * 64 + kg * 16);
            #pragma unroll
            for (int m = 0; m < 4; ++m)
                #pragma unroll
                for (int n = 0; n < 4; ++n)
                    acc[m][n] = MFMA16x16x32(af[m], bfr[n], acc[m][n]);
        }
        __syncthreads();
    }

    const int whichB = bn0 / Cq;               // 0=Q 1=K 2=V, block-uniform
    char* Lt = (char*)&As[0][0];               // 32 KB reuse; rows of 256B
    #pragma unroll
    for (int mi = 0; mi < 4; ++mi) {
        #pragma unroll
        for (int r = 0; r < 4; ++r) {
            const int m = wr * 64 + mi * 16 + kg * 4 + r;
            #pragma unroll
            for (int ni = 0; ni < 4; ++ni) {
                const int n = wc * 64 + ni * 16 + lane16;
                float v = acc[mi][ni][r] + bias[bn0 + n];
                if (whichB == 0) v *= 0.18033688011112042f;  // 1/8 * log2(e)
                int a;
                if (whichB < 2) a = m * 256 + ((n * 2) ^ ((m & 7) << 4));
                else            a = n * 256 + ((m * 2) ^ ((n & 7) << 4));
                *reinterpret_cast<bf16*>(Lt + a) = (bf16)v;
            }
        }
    }
    __syncthreads();
    const int bb = bm0 >> 10, tt0 = bm0 & 1023;
    if (whichB == 0) {
        #pragma unroll
        for (int j = 0; j < 8; ++j) {
            const int c = j * 256 + tid;       // 2048 16B-chunks
            const int m = c >> 4, nc = c & 15;
            bf16x8 val = *reinterpret_cast<bf16x8*>(Lt + m * 256 + ((nc * 16) ^ ((m & 7) << 4)));
            const int gcol0 = bn0 + nc * 8;
            const int h = gcol0 >> 6;
            const int d0 = gcol0 & 63;
            *reinterpret_cast<bf16x8*>(Qo + (((size_t)bb * Hq + h) * Tq + tt0 + m) * Dq + d0) = val;
        }
    } else if (whichB == 1) {
        // K8: chunk = 8 consecutive d at one t; consecutive m -> contiguous
        #pragma unroll
        for (int j = 0; j < 8; ++j) {
            const int c = j * 256 + tid;
            const int m = c & 127, nc = c >> 7;
            bf16x8 val = *reinterpret_cast<bf16x8*>(Lt + m * 256 + ((nc * 16) ^ ((m & 7) << 4)));
            const int hn = bn0 + nc * 8 - Cq;
            const int h = hn >> 6, d8 = (hn >> 3) & 7;
            *reinterpret_cast<bf16x8*>(
                K8 + ((((size_t)bb * Hq + h) * 8 + d8) * Tq + tt0 + m) * 8) = val;
        }
    } else {
        // V8: chunk = 8 consecutive t at one d; consecutive d -> contiguous
        #pragma unroll
        for (int j = 0; j < 8; ++j) {
            const int c = j * 256 + tid;
            const int d6 = c & 63, rest = c >> 6;
            const int hh = rest & 1, mc = rest >> 1;
            const int n = hh * 64 + d6;
            bf16x8 val = *reinterpret_cast<bf16x8*>(Lt + n * 256 + ((mc * 16) ^ ((n & 7) << 4)));
            const int hn = bn0 + n - 2 * Cq;
            const int h = hn >> 6, d = hn & 63;
            *reinterpret_cast<bf16x8*>(
                V8 + ((((size_t)bb * Hq + h) * 128 + (tt0 >> 3) + mc) * Dq + d) * 8) = val;
        }
    }
}

// ---------------- Flash causal attention: 32-row waves + T13 defer-max -------
__global__ __launch_bounds__(256) void attn_mfma(const bf16* __restrict__ Q,
                                                 const bf16* __restrict__ K8,
                                                 const bf16* __restrict__ V8,
                                                 bf16* __restrict__ Y) {
    const int tid = threadIdx.x;
    const int w = tid >> 6, l = tid & 63;
    const int l31 = l & 31, hi = l >> 5;
    const int g = blockIdx.x / 96;             // 0..7, heaviest first
    const int bh = blockIdx.x % 96;            // same head -> same XCD (96%8==0)
    const int qs = 31 - (g * 4 + w);           // q32-subtile 0..31
    const int q0 = qs * 32;
    const int nt = (qs >> 1) + 1;              // KV 64-tiles
    const size_t hoff = (size_t)bh * Tq * Dq;
    const size_t base8 = (size_t)bh * (Tq * Dq);
    const int q0g = q0 + l31;                  // this lane's global q row

    bf16x8 qf[4];
    #pragma unroll
    for (int ds = 0; ds < 4; ++ds)
        qf[ds] = *reinterpret_cast<const bf16x8*>(
            Q + hoff + (size_t)q0g * Dq + ds * 16 + hi * 8);

    f32x16 o[2] = {};                           // [dh]
    float m_ = -INFINITY, l_ = 0.f;

    for (int t = 0; t < nt; ++t) {
        const bool diag = (t == nt - 1);
        const bool half = diag && !(qs & 1);    // upper 32 kcols fully masked
        bf16x8 kf[2][4];
        #pragma unroll
        for (int ds = 0; ds < 4; ++ds)
            kf[0][ds] = *reinterpret_cast<const bf16x8*>(
                K8 + base8 + ((size_t)(ds * 2 + hi) * Tq + t * 64 + l31) * 8);
        if (!half) {
            #pragma unroll
            for (int ds = 0; ds < 4; ++ds)
                kf[1][ds] = *reinterpret_cast<const bf16x8*>(
                    K8 + base8 + ((size_t)(ds * 2 + hi) * Tq + t * 64 + 32 + l31) * 8);
        }
        bf16x8 vf[4][2];
        #pragma unroll
        for (int ks = 0; ks < 2; ++ks)
            #pragma unroll
            for (int dh = 0; dh < 2; ++dh)
                vf[ks][dh] = *reinterpret_cast<const bf16x8*>(
                    V8 + base8 + ((size_t)(t * 8 + ks * 2 + hi) * Dq + dh * 32 + l31) * 8);
        if (!half) {
            #pragma unroll
            for (int ks = 2; ks < 4; ++ks)
                #pragma unroll
                for (int dh = 0; dh < 2; ++dh)
                    vf[ks][dh] = *reinterpret_cast<const bf16x8*>(
                        V8 + base8 + ((size_t)(t * 8 + ks * 2 + hi) * Dq + dh * 32 + l31) * 8);
        }

        f32x16 s[2] = {};
        #pragma unroll
        for (int ds = 0; ds < 4; ++ds) s[0] = MFMA32x32x16(kf[0][ds], qf[ds], s[0]);
        if (!half) {
            #pragma unroll
            for (int ds = 0; ds < 4; ++ds) s[1] = MFMA32x32x16(kf[1][ds], qf[ds], s[1]);
        }
        if (diag) {
            #pragma unroll
            for (int reg = 0; reg < 16; ++reg) {
                const int kg_ = t * 64 + (reg & 3) + 8 * (reg >> 2) + 4 * hi;
                if (kg_ > q0g) s[0][reg] = -INFINITY;
                if (!half && kg_ + 32 > q0g) s[1][reg] = -INFINITY;
            }
        }
        // 4-way tree max
        float pm0 = -INFINITY, pm1 = -INFINITY, pm2 = -INFINITY, pm3 = -INFINITY;
        #pragma unroll
        for (int reg = 0; reg < 16; reg += 4) {
            pm0 = fmaxf(pm0, s[0][reg + 0]);
            pm1 = fmaxf(pm1, s[0][reg + 1]);
            pm2 = fmaxf(pm2, s[0][reg + 2]);
            pm3 = fmaxf(pm3, s[0][reg + 3]);
        }
        if (!half) {
            #pragma unroll
            for (int reg = 0; reg < 16; reg += 4) {
                pm0 = fmaxf(pm0, s[1][reg + 0]);
                pm1 = fmaxf(pm1, s[1][reg + 1]);
                pm2 = fmaxf(pm2, s[1][reg + 2]);
                pm3 = fmaxf(pm3, s[1][reg + 3]);
            }
        }
        float pmax = fmaxf(fmaxf(pm0, pm1), fmaxf(pm2, pm3));
        pmax = fmaxf(pmax, __shfl_xor(pmax, 32));
        // T13 defer-max: rescale only when max grew beyond headroom.
        if (!__all(pmax <= m_ + 8.f)) {
            const float mn = fmaxf(m_, pmax);
            const float alpha = exp2f(m_ - mn);
            m_ = mn;
            l_ *= alpha;
            o[0] *= alpha;
            o[1] *= alpha;
        }
        // 4-way tree sum
        float ls0 = 0.f, ls1 = 0.f, ls2 = 0.f, ls3 = 0.f;
        #pragma unroll
        for (int reg = 0; reg < 16; reg += 4) {
            const float p0 = exp2f(s[0][reg + 0] - m_);
            const float p1 = exp2f(s[0][reg + 1] - m_);
            const float p2 = exp2f(s[0][reg + 2] - m_);
            const float p3 = exp2f(s[0][reg + 3] - m_);
            s[0][reg + 0] = p0; ls0 += p0;
            s[0][reg + 1] = p1; ls1 += p1;
            s[0][reg + 2] = p2; ls2 += p2;
            s[0][reg + 3] = p3; ls3 += p3;
        }
        if (!half) {
            #pragma unroll
            for (int reg = 0; reg < 16; reg += 4) {
                const float p0 = exp2f(s[1][reg + 0] - m_);
                const float p1 = exp2f(s[1][reg + 1] - m_);
                const float p2 = exp2f(s[1][reg + 2] - m_);
                const float p3 = exp2f(s[1][reg + 3] - m_);
                s[1][reg + 0] = p0; ls0 += p0;
                s[1][reg + 1] = p1; ls1 += p1;
                s[1][reg + 2] = p2; ls2 += p2;
                s[1][reg + 3] = p3; ls3 += p3;
            }
        }
        l_ += (ls0 + ls1) + (ls2 + ls3);
        // P-pack via permlane32_swap
        bf16x8 pa[4];
        #pragma unroll
        for (int g2 = 0; g2 < 2; ++g2) {
            const int rb = g2 * 8;
            unsigned u01 = cvtpk_bf16(s[0][rb + 0], s[0][rb + 1]);
            unsigned u23 = cvtpk_bf16(s[0][rb + 2], s[0][rb + 3]);
            unsigned u45 = cvtpk_bf16(s[0][rb + 4], s[0][rb + 5]);
            unsigned u67 = cvtpk_bf16(s[0][rb + 6], s[0][rb + 7]);
            permlane32_swap(u01, u45);
            permlane32_swap(u23, u67);
            u32x4 wv;
            wv[0] = u01; wv[1] = u23; wv[2] = u45; wv[3] = u67;
            pa[g2] = __builtin_bit_cast(bf16x8, wv);
        }
        if (!half) {
            #pragma unroll
            for (int g2 = 0; g2 < 2; ++g2) {
                const int rb = g2 * 8;
                unsigned u01 = cvtpk_bf16(s[1][rb + 0], s[1][rb + 1]);
                unsigned u23 = cvtpk_bf16(s[1][rb + 2], s[1][rb + 3]);
                unsigned u45 = cvtpk_bf16(s[1][rb + 4], s[1][rb + 5]);
                unsigned u67 = cvtpk_bf16(s[1][rb + 6], s[1][rb + 7]);
                permlane32_swap(u01, u45);
                permlane32_swap(u23, u67);
                u32x4 wv;
                wv[0] = u01; wv[1] = u23; wv[2] = u45; wv[3] = u67;
                pa[2 + g2] = __builtin_bit_cast(bf16x8, wv);
            }
        }
        #pragma unroll
        for (int ks = 0; ks < 2; ++ks)
            #pragma unroll
            for (int dh = 0; dh < 2; ++dh)
                o[dh] = MFMA32x32x16(vf[ks][dh], pa[ks], o[dh]);
        if (!half) {
            #pragma unroll
            for (int ks = 2; ks < 4; ++ks)
                #pragma unroll
                for (int dh = 0; dh < 2; ++dh)
                    o[dh] = MFMA32x32x16(vf[ks][dh], pa[ks], o[dh]);
        }
    }

    const int bb = bh / Hq, h = bh - bb * Hq;
    const float ltot = l_ + __shfl_xor(l_, 32);
    const float inv = 1.f / ltot;
    bf16* yp = Y + ((size_t)bb * Tq + q0g) * Cq + h * Dq;
    #pragma unroll
    for (int dh = 0; dh < 2; ++dh)
        #pragma unroll
        for (int rg = 0; rg < 4; ++rg) {
            const int d0 = 8 * rg + 4 * hi + 32 * dh;
            bf16x4 ov;
            #pragma unroll
            for (int j = 0; j < 4; ++j) ov[j] = (bf16)(o[dh][rg * 4 + j] * inv);
            *reinterpret_cast<bf16x4*>(yp + d0) = ov;
        }
}

// ---------------- Proj GEMM: 128x128 dbuf + LDS-staged f32 epilogue ----------
__global__ __launch_bounds__(256) void gemm_proj(const bf16* __restrict__ A,
                                                 const bf16* __restrict__ Bt,
                                                 const float* __restrict__ bias,
                                                 float* __restrict__ out) {
    __shared__ bf16 As[2][128 * 64];
    __shared__ bf16 Bs[2][128 * 64];
    const int tid = threadIdx.x;
    const int w = tid >> 6, l = tid & 63;
    const int lane16 = l & 15, kg = l >> 4;
    const int wr = w >> 1, wc = w & 1;
    const int flat = blockIdx.x;
    const int nid = (flat & 7) * 48 + (flat >> 3);
    const int bn0 = (nid % 6) * 128, bm0 = (nid / 6) * 128;

    auto stage = [&](int k0, int buf) {
        #pragma unroll
        for (int j = 0; j < 4; ++j) {
            const int q8 = w * 4 + j;
            const int r  = q8 * 8 + (l >> 3);
            const int c16 = (l & 7) ^ (r & 7);
            gload16(A + (size_t)(bm0 + r) * Cq + k0 + c16 * 8, &As[buf][q8 * 512]);
            gload16(Bt + (size_t)(bn0 + r) * Cq + k0 + c16 * 8, &Bs[buf][q8 * 512]);
        }
    };

    f32x4 acc[4][4] = {};
    stage(0, 0);
    __syncthreads();
    for (int kt = 0; kt < 12; ++kt) {
        if (kt < 11) stage((kt + 1) * 64, (kt + 1) & 1);
        bf16* Ac = As[kt & 1];
        bf16* Bc = Bs[kt & 1];
        #pragma unroll
        for (int ks = 0; ks < 2; ++ks) {
            bf16x8 af[4], bfr[4];
            #pragma unroll
            for (int m = 0; m < 4; ++m)
                af[m] = lds_v8(Ac, wr * 64 + m * 16 + lane16, ks * 64 + kg * 16);
            #pragma unroll
            for (int n = 0; n < 4; ++n)
                bfr[n] = lds_v8(Bc, wc * 64 + n * 16 + lane16, ks * 64 + kg * 16);
            #pragma unroll
            for (int m = 0; m < 4; ++m)
                #pragma unroll
                for (int n = 0; n < 4; ++n)
                    acc[m][n] = MFMA16x16x32(af[m], bfr[n], acc[m][n]);
        }
        __syncthreads();
    }

    char* L32 = (char*)&As[0][0];   // 32 KB: 128 rows x 64 f32 (256B rows)
    #pragma unroll
    for (int half = 0; half < 2; ++half) {
        if (wc == half) {
            #pragma unroll
            for (int mi = 0; mi < 4; ++mi)
                #pragma unroll
                for (int r = 0; r < 4; ++r) {
                    const int m = wr * 64 + mi * 16 + kg * 4 + r;
                    #pragma unroll
                    for (int ni = 0; ni < 4; ++ni) {
                        const int nl = ni * 16 + lane16;
                        const float v = acc[mi][ni][r] + bias[bn0 + half * 64 + nl];
                        *reinterpret_cast<float*>(L32 + m * 256 + ((nl * 4) ^ ((m & 7) << 4))) = v;
                    }
                }
        }
        __syncthreads();
        #pragma unroll
        for (int j = 0; j < 8; ++j) {
            const int c = j * 256 + tid;
            const int m = c >> 4, nc = c & 15;
            float4 val = *reinterpret_cast<float4*>(L32 + m * 256 + ((nc * 16) ^ ((m & 7) << 4)));
            *reinterpret_cast<float4*>(out + (size_t)(bm0 + m) * Cq + bn0 + half * 64 + nc * 4) = val;
        }
        __syncthreads();
    }
}

extern "C" void kernel_launch(void* const* d_in, const int* in_sizes, int n_in,
                              void* d_out, int out_size, void* d_ws, size_t ws_size,
                              hipStream_t stream) {
    const float* x      = (const float*)d_in[0];
    const float* w_attn = (const float*)d_in[1];
    const float* b_attn = (const float*)d_in[2];
    const float* w_proj = (const float*)d_in[3];
    const float* b_proj = (const float*)d_in[4];
    float* out = (float*)d_out;

    char* ws = (char*)d_ws;
    bf16* Ax  = (bf16*)ws; ws += (size_t)MROWS * Cq * 2;
    bf16* WaT = (bf16*)ws; ws += (size_t)N_QKV * Cq * 2;
    bf16* WpT = (bf16*)ws; ws += (size_t)Cq * Cq * 2;
    bf16* Qw  = (bf16*)ws; ws += (size_t)MROWS * Cq * 2;   // [B,H,T,D], x0.125*log2e
    bf16* K8w = (bf16*)ws; ws += (size_t)MROWS * Cq * 2;   // [B,H,D/8,T,8]
    bf16* V8w = (bf16*)ws; ws += (size_t)MROWS * Cq * 2;   // [B,H,T/8,D,8]
    bf16* Yw  = (bf16*)ws; ws += (size_t)MROWS * Cq * 2;   // attn out [M][C]

    prep<<<dim3(NA_CONV + NB_WA + NB_WP), 256, 0, stream>>>(x, w_attn, w_proj, Ax, WaT, WpT);
    gemm_qkv<<<dim3(1152), 256, 0, stream>>>(Ax, WaT, b_attn, Qw, K8w, V8w);
    attn_mfma<<<dim3(768), 256, 0, stream>>>(Qw, K8w, V8w, Yw);
    gemm_proj<<<dim3(384), 256, 0, stream>>>(Yw, WpT, b_proj, out);
}